// Round 1
// baseline (115.097 us; speedup 1.0000x reference)
//
#include <hip/hip_runtime.h>

#define N_PIX   230400
#define K_SEG   21
#define GT_MAX  21
#define TILE    128
#define TPAD    132          // pad to multiple of 4 (float4-aligned), 132 mod 32 = 4
#define EPSF    1e-6f
#define BIGF    1.0e6f
#define NBLK    450
#define TPB     4            // tiles per block: 450*4*128 = 230400 exactly
#define NTHREADS 512

__global__ __launch_bounds__(NTHREADS, 2)
void ce_accum_kernel(const float* __restrict__ seg,   // (N, K) row-major
                     const int*   __restrict__ gt,    // (GT_MAX, N)
                     const int*   __restrict__ gpn_ptr,
                     float*       __restrict__ acc_out) // layout p = gcol*21 + k
{
    __shared__ float d_lds [K_SEG * TPAD];
    __shared__ float l1_lds[K_SEG * TPAD];
    __shared__ float gt_lds[GT_MAX * TPAD];

    const int G    = *gpn_ptr;
    const int tid  = threadIdx.x;
    const int p    = tid;
    const int k    = p % K_SEG;
    const int gcol = p / K_SEG;
    const bool active = (p < K_SEG * (G + 1));   // last column accumulates sum(l1p)

    float acc = 0.0f;

    for (int i = 0; i < TPB; ++i) {
        const int n0 = (blockIdx.x * TPB + i) * TILE;

        // ---- stage seg -> d, l1p (contiguous global read of 21*128 floats) ----
        for (int e = tid; e < K_SEG * TILE; e += NTHREADS) {
            float s  = seg[n0 * K_SEG + e];
            int   kk = e % K_SEG;
            int   nn = e / K_SEG;
            float lp = __logf(s + EPSF);
            float l1 = __logf(1.0f - s + EPSF);
            d_lds [kk * TPAD + nn] = lp - l1;
            l1_lds[kk * TPAD + nn] = l1;
        }
        // ---- stage gt (int -> float), coalesced per-g runs of 128 ----
        for (int e = tid; e < G * TILE; e += NTHREADS) {
            int gg = e / TILE;
            int nn = e % TILE;
            gt_lds[gg * TPAD + nn] = (float)gt[gg * N_PIX + n0 + nn];
        }
        __syncthreads();

        if (active) {
            if (gcol < G) {
                const float4* dp = (const float4*)&d_lds [k    * TPAD];
                const float4* gp = (const float4*)&gt_lds[gcol * TPAD];
                #pragma unroll 8
                for (int n4 = 0; n4 < TILE / 4; ++n4) {
                    float4 d = dp[n4];
                    float4 g = gp[n4];
                    acc += d.x * g.x + d.y * g.y + d.z * g.z + d.w * g.w;
                }
            } else {  // gcol == G: plain sum of l1p for this k
                const float4* lp1 = (const float4*)&l1_lds[k * TPAD];
                #pragma unroll 8
                for (int n4 = 0; n4 < TILE / 4; ++n4) {
                    float4 l = lp1[n4];
                    acc += l.x + l.y + l.z + l.w;
                }
            }
        }
        __syncthreads();
    }

    if (active) atomicAdd(&acc_out[p], acc);
}

__global__ void finalize_kernel(const float* __restrict__ acc,
                                const int*   __restrict__ gpn_ptr,
                                int*         __restrict__ out)
{
    __shared__ float ce_val  [K_SEG];
    __shared__ int   matching[K_SEG];
    __shared__ int   best_k  [GT_MAX];
    __shared__ int   max_index_s;

    const int G = *gpn_ptr;
    const int t = threadIdx.x;

    // per-k argmin over g (strict < == first-min, matches jnp.argmin)
    if (t < K_SEG) {
        const float B    = acc[G * K_SEG + t];     // sum of l1p for this k
        const float invn = 1.0f / (float)N_PIX;
        float best = INFINITY;
        int   bg   = 0;
        for (int g = 0; g < G; ++g) {
            float ce = -(acc[g * K_SEG + t] + B) * invn;
            if (ce < best) { best = ce; bg = g; }
        }
        ce_val[t]   = best;
        matching[t] = bg;
    }
    __syncthreads();

    if (t == 0) {
        int mx = 0;
        for (int kk = 0; kk < K_SEG; ++kk) mx = max(mx, matching[kk]);
        max_index_s = mx + 1;
    }
    // greedy dedup: per gt plane, first k with minimal ce_val among matched
    if (t < G) {
        float best = BIGF;
        int   bk   = 0;          // argmin of all-BIG row is 0 (first index)
        for (int kk = 0; kk < K_SEG; ++kk) {
            float v = (matching[kk] == t) ? ce_val[kk] : BIGF;
            if (v < best) { best = v; bk = kk; }
        }
        best_k[t] = bk;
    }
    __syncthreads();

    if (t < K_SEG) {
        int m = matching[t];
        out[t] = (best_k[m] == t) ? m : max_index_s;
    }
}

extern "C" void kernel_launch(void* const* d_in, const int* in_sizes, int n_in,
                              void* d_out, int out_size, void* d_ws, size_t ws_size,
                              hipStream_t stream)
{
    const float* seg = (const float*)d_in[0];   // (230400, 21) fp32
    const int*   gt  = (const int*)  d_in[1];   // (21, 480, 480) int32
    const int*   gpn = (const int*)  d_in[2];   // scalar int (gt_plane_num)
    int*         out = (int*)d_out;             // (21,) int32
    float*       acc = (float*)d_ws;            // 22*21 fp32 accumulators

    hipMemsetAsync(acc, 0, K_SEG * (GT_MAX + 1) * sizeof(float), stream);
    ce_accum_kernel<<<NBLK, NTHREADS, 0, stream>>>(seg, gt, gpn, acc);
    finalize_kernel<<<1, 64, 0, stream>>>(acc, gpn, out);
}